// Round 3
// baseline (7067.461 us; speedup 1.0000x reference)
//
#include <hip/hip_runtime.h>
#include <math.h>

// ============================================================================
// Persistent per-signal FFT ISTA solver, radix-8, register-resident edition.
//
// Math (identical to the r1/r2 verified versions):
//   u_{t+1} = u_t - 0.05*(I-P)*clamp20(u_t),  u_0 = 100*DCT(scatter(x[idxs]))
//   P*h = DCT2(mask(IDCT(h))) via FFT+ (DIF) then FFT- (DIT).
//   out = 0.01*IDCT(u_99 - 0.05*clamp20(u_99)).
//
// FFT decomposition: 2048 = 8*8*8*4, 256 threads/signal, 8 cf pts/thread.
//   Slot p = 256b' + 32c' + 4d' + e' holds Y[m], m = b' + 8c' + 64d' + 512e'.
//   LDS XOR-swizzle swz(p) = p ^ (((p>>5)&7)<<2): S0/T3, S1/T2, S2/T1 all hit
//   the 4-dword/bank minimum; S3/T0 float4 quad is 2-way (free).
//   S3 + measurement mask + T0 fuse in registers (8-bit mask/thread).
//
// r2 -> r3 change: NO local arrays anywhere. Twiddles are 21 named cf scalars,
// butterflies take 8 named references, DCT cos/sin tables are literal
// immediates in unrolled macros. r2 spilled Wp/Op/Lp + CR/SR to scratch
// (VGPR=64, FETCH 21 GB/dispatch); this keeps them in VGPRs.
// ============================================================================

#define PIF 3.14159265358979323846f
#define C0F 0.022097086912079608f      // sqrt(1/2048)
#define TWOC0 0.044194173824159216f    // 2*sqrt(1/2048)
#define CNF 0.03125f                   // sqrt(2/2048)
#define SPW 3                          // signals per block; grid = 3072/3 = 1024

typedef float2 cf;

__device__ __forceinline__ int load_idx(const int* p, int j) {
    return (p[1] == 0) ? p[2 * j] : p[j];   // int64 (lo,0) pairs or int32
}
__device__ __forceinline__ int pinv(int m) {   // frequency -> slot
    return ((m & 7) << 8) | (((m >> 3) & 7) << 5) | (((m >> 6) & 7) << 2) | ((m >> 9) & 3);
}
__device__ __forceinline__ int permf(int p) {  // slot -> frequency
    return (p >> 8) | (((p >> 5) & 7) << 3) | (((p >> 2) & 7) << 6) | ((p & 3) << 9);
}
__device__ __forceinline__ float clamp20(float g) {
    return fminf(fmaxf(20.f * g, -1.f), 1.f);
}
__device__ __forceinline__ cf cadd(cf a, cf b) { return make_float2(a.x + b.x, a.y + b.y); }
__device__ __forceinline__ cf csub(cf a, cf b) { return make_float2(a.x - b.x, a.y - b.y); }
__device__ __forceinline__ cf cmul(cf a, cf b) {
    return make_float2(a.x * b.x - a.y * b.y, a.x * b.y + a.y * b.x);
}
__device__ __forceinline__ cf cmulc(cf a, cf b) {   // a * conj(b)
    return make_float2(a.x * b.x + a.y * b.y, a.y * b.x - a.x * b.y);
}
template <int S> __device__ __forceinline__ cf imul(cf z) {  // (S*i)*z
    return (S > 0) ? make_float2(-z.y, z.x) : make_float2(z.y, -z.x);
}

// DFT-8 over named refs: v_j = sum_b v_in_b * w8^{S*b*j}
template <int S>
__device__ __forceinline__ void dft8r(cf& v0, cf& v1, cf& v2, cf& v3,
                                      cf& v4, cf& v5, cf& v6, cf& v7) {
    const float R2 = 0.70710678118654752f;
    cf A0 = cadd(v0, v4), D0 = csub(v0, v4);
    cf A1 = cadd(v1, v5), D1 = csub(v1, v5);
    cf A2 = cadd(v2, v6), D2 = csub(v2, v6);
    cf A3 = cadd(v3, v7), D3 = csub(v3, v7);
    const cf w8  = make_float2(R2, (S > 0) ? R2 : -R2);
    const cf w83 = make_float2(-R2, (S > 0) ? R2 : -R2);
    D1 = cmul(D1, w8);
    D2 = imul<S>(D2);
    D3 = cmul(D3, w83);
    cf E0 = cadd(A0, A2), E1 = csub(A0, A2);
    cf O0 = cadd(A1, A3), O1 = imul<S>(csub(A1, A3));
    cf F0 = cadd(D0, D2), F1 = csub(D0, D2);
    cf P0 = cadd(D1, D3), P1 = imul<S>(csub(D1, D3));
    v0 = cadd(E0, O0); v2 = cadd(E1, O1);
    v4 = csub(E0, O0); v6 = csub(E1, O1);
    v1 = cadd(F0, P0); v3 = cadd(F1, P1);
    v5 = csub(F0, P0); v7 = csub(F1, P1);
}

template <int S>
__device__ __forceinline__ void dft4r(cf& v0, cf& v1, cf& v2, cf& v3) {
    cf E0 = cadd(v0, v2), E1 = csub(v0, v2);
    cf O0 = cadd(v1, v3), O1 = imul<S>(csub(v1, v3));
    v0 = cadd(E0, O0); v1 = cadd(E1, O1);
    v2 = csub(E0, O0); v3 = csub(E1, O1);
}

// cos/sin(pi*b/16) literals, b = 0..7
#define CRL0 1.0f
#define CRL1 0.980785280403230449f
#define CRL2 0.923879532511286756f
#define CRL3 0.831469612302545237f
#define CRL4 0.707106781186547524f
#define CRL5 0.555570233019602225f
#define CRL6 0.382683432365089772f
#define CRL7 0.195090322016128268f
#define SRL0 0.0f
#define SRL1 CRL7
#define SRL2 CRL6
#define SRL3 CRL5
#define SRL4 CRL4
#define SRL5 CRL3
#define SRL6 CRL2
#define SRL7 CRL1

#define SWZ(p) ((p) ^ ((((p) >> 5) & 7) << 2))
#define A0j(j) (tsw + 256 * (j))
#define A1j(j) ((s1b ^ ((j) << 2)) + 32 * (j) + 256 * t5)
#define A2j(j) (s2k + 4 * ((j) ^ s2c) + 32 * s2c + 256 * t5)

#define LOAD8(A) cf v0 = wk[A(0)], v1 = wk[A(1)], v2 = wk[A(2)], v3 = wk[A(3)], \
                    v4 = wk[A(4)], v5 = wk[A(5)], v6 = wk[A(6)], v7 = wk[A(7)]
#define STORE8(A) wk[A(0)] = v0; wk[A(1)] = v1; wk[A(2)] = v2; wk[A(3)] = v3; \
                  wk[A(4)] = v4; wk[A(5)] = v5; wk[A(6)] = v6; wk[A(7)] = v7
#define TWF(P) v1 = cmul(v1, P##1); v2 = cmul(v2, P##2); v3 = cmul(v3, P##3); \
               v4 = cmul(v4, P##4); v5 = cmul(v5, P##5); v6 = cmul(v6, P##6); \
               v7 = cmul(v7, P##7)
#define TWB(P) v1 = cmulc(v1, P##1); v2 = cmulc(v2, P##2); v3 = cmulc(v3, P##3); \
               v4 = cmulc(v4, P##4); v5 = cmulc(v5, P##5); v6 = cmulc(v6, P##6); \
               v7 = cmulc(v7, P##7)

#define DIFMID(A, P) { LOAD8(A); dft8r<1>(v0, v1, v2, v3, v4, v5, v6, v7); \
                       TWF(P); STORE8(A); }
#define DITMID(A, P) { LOAD8(A); TWB(P); dft8r<-1>(v0, v1, v2, v3, v4, v5, v6, v7); \
                       STORE8(A); }

// V-build for DIF head (fin selects iteration vs final nonlinearity)
#define MKVB(b, vo) { \
    const int k_ = t + 256 * (b); \
    const int kN_ = (2048 - k_) & 2047; \
    const float gk_ = g[k_], gN_ = g[kN_]; \
    float hk_, hN_; \
    if (fin) { hk_ = gk_ - 0.05f * clamp20(gk_); hN_ = gN_ - 0.05f * clamp20(gN_); } \
    else     { hk_ = clamp20(gk_);               hN_ = clamp20(gN_); } \
    const bool kz_ = ((b) == 0) && (t == 0); \
    const float Xk_ = (kz_ ? TWOC0 : CNF) * hk_; \
    const float XN_ = kz_ ? 0.f : CNF * hN_; \
    const float cc_ = c0a * (CRL##b) - s0a * (SRL##b); \
    const float ss_ = s0a * (CRL##b) + c0a * (SRL##b); \
    vo = make_float2(0.5f * (Xk_ * cc_ + XN_ * ss_), 0.5f * (Xk_ * ss_ - XN_ * cc_)); }

#define HEADS0(finv) { \
    const bool fin = (finv); \
    cf v0, v1, v2, v3, v4, v5, v6, v7; \
    MKVB(0, v0) MKVB(1, v1) MKVB(2, v2) MKVB(3, v3) \
    MKVB(4, v4) MKVB(5, v5) MKVB(6, v6) MKVB(7, v7) \
    dft8r<1>(v0, v1, v2, v3, v4, v5, v6, v7); \
    TWF(W); STORE8(A0j); }

#define TAILJ(j) { \
    const int k_ = t + 256 * (j); \
    const float cc_ = c0a * (CRL##j) - s0a * (SRL##j); \
    const float ss_ = s0a * (CRL##j) + c0a * (SRL##j); \
    const float Cv_ = v##j.x * cc_ + v##j.y * ss_; \
    const float u_ = ((((j) == 0) && (t == 0)) ? C0F : CNF) * Cv_; \
    if (init) g[k_] = u_; \
    else { const float gk_ = g[k_]; g[k_] = gk_ + 0.05f * (u_ - clamp20(gk_)); } }

#define TAILT3(initv) { \
    const bool init = (initv); \
    LOAD8(A0j); TWB(W); dft8r<-1>(v0, v1, v2, v3, v4, v5, v6, v7); \
    TAILJ(0) TAILJ(1) TAILJ(2) TAILJ(3) TAILJ(4) TAILJ(5) TAILJ(6) TAILJ(7) }

// S3 + mask + T0, all in registers (one 16-pt quad, q = 0 or 1)
#define QUADMASK(q) { \
    const int pb_ = 8 * t + 4 * (q); \
    const int a_ = SWZ(pb_); \
    float4 lo_ = *(const float4*)(&wk[a_]); \
    float4 hi_ = *(const float4*)(&wk[a_ + 2]); \
    cf u0 = make_float2(lo_.x, lo_.y), u1 = make_float2(lo_.z, lo_.w); \
    cf u2 = make_float2(hi_.x, hi_.y), u3 = make_float2(hi_.z, hi_.w); \
    dft4r<1>(u0, u1, u2, u3); \
    u0 = make_float2(u0.x * (float)((msk >> (4 * (q) + 0)) & 1u), 0.f); \
    u1 = make_float2(u1.x * (float)((msk >> (4 * (q) + 1)) & 1u), 0.f); \
    u2 = make_float2(u2.x * (float)((msk >> (4 * (q) + 2)) & 1u), 0.f); \
    u3 = make_float2(u3.x * (float)((msk >> (4 * (q) + 3)) & 1u), 0.f); \
    dft4r<-1>(u0, u1, u2, u3); \
    *(float4*)(&wk[a_])     = make_float4(u0.x, u0.y, u1.x, u1.y); \
    *(float4*)(&wk[a_ + 2]) = make_float4(u2.x, u2.y, u3.x, u3.y); }

__global__ __launch_bounds__(256, 4) void ista_fft_kernel(
    const float* __restrict__ x, const int* __restrict__ idxs,
    float* __restrict__ out)
{
    __shared__ __align__(16) cf wk[2048];   // 16 KB, swizzled slot space
    __shared__ float g[2048];               // 8 KB
    __shared__ unsigned mbm[64];

    const int t = threadIdx.x;
    const int t5 = t >> 5;
    const int s1b = t & 31;
    const int s2k = t & 3, s2c = (t >> 2) & 7;
    const int tsw = SWZ(t);

    if (t < 64) mbm[t] = 0u;
    __syncthreads();

    const int mi0 = load_idx(idxs, t), mi1 = load_idx(idxs, t + 256);
    const int yd0 = (mi0 & 1) ? (2047 - (mi0 >> 1)) : (mi0 >> 1);
    const int yd1 = (mi1 & 1) ? (2047 - (mi1 >> 1)) : (mi1 >> 1);
    const int pm0 = pinv(yd0), pm1 = pinv(yd1);
    atomicOr(&mbm[pm0 >> 5], 1u << (pm0 & 31));
    atomicOr(&mbm[pm1 >> 5], 1u << (pm1 & 31));
    const int sl0 = SWZ(pm0), sl1 = SWZ(pm1);
    __syncthreads();
    const unsigned msk = (mbm[t >> 2] >> ((t & 3) * 8)) & 0xffu;

    // thread-invariant twiddles, all in named registers
    float s0a, c0a; sincosf(PIF * (float)t * (1.f / 4096.f), &s0a, &c0a);
    float sww, cww; sincosf(2.f * PIF * (float)t   * (1.f / 2048.f), &sww, &cww);
    float soo, coo; sincosf(2.f * PIF * (float)s1b * (1.f / 256.f),  &soo, &coo);
    float sll, cll; sincosf(2.f * PIF * (float)s2k * (1.f / 32.f),   &sll, &cll);
    const cf W1 = make_float2(cww, sww);
    const cf W2 = cmul(W1, W1), W3 = cmul(W2, W1), W4 = cmul(W2, W2),
             W5 = cmul(W3, W2), W6 = cmul(W3, W3), W7 = cmul(W4, W3);
    const cf O1 = make_float2(coo, soo);
    const cf O2 = cmul(O1, O1), O3 = cmul(O2, O1), O4 = cmul(O2, O2),
             O5 = cmul(O3, O2), O6 = cmul(O3, O3), O7 = cmul(O4, O3);
    const cf L1 = make_float2(cll, sll);
    const cf L2 = cmul(L1, L1), L3 = cmul(L2, L1), L4 = cmul(L2, L2),
             L5 = cmul(L3, L2), L6 = cmul(L3, L3), L7 = cmul(L4, L3);

#pragma unroll 1
    for (int s = 0; s < SPW; ++s) {
        const int r = blockIdx.x * SPW + s;

        // ---- init: wk = scatter(100*x[r, idxs]) in swizzled slot space ----
#pragma unroll
        for (int j = 0; j < 8; ++j) wk[t + 256 * j] = make_float2(0.f, 0.f);
        __syncthreads();
        wk[sl0] = make_float2(100.f * x[(size_t)r * 2048 + mi0], 0.f);
        wk[sl1] = make_float2(100.f * x[(size_t)r * 2048 + mi1], 0.f);
        __syncthreads();
        {   // T0 (input already masked, no mask factors needed)
            QUADMASK(0) QUADMASK(1)
            // NOTE: QUADMASK applies S3(fwd)+mask+T0; for init we need plain
            // T0 only — but the input is real & already masked, and S3(fwd)
            // then mask then T0 is NOT identity on it. Use plain T0 instead.
        }
        // The above comment is resolved by overwriting: redo plain T0 below.
        __syncthreads();
        // (Correction path: recompute T0 cleanly — see init_t0 below.)
        // To keep a single code path, the scatter is re-done and plain T0 run.
#pragma unroll
        for (int j = 0; j < 8; ++j) wk[t + 256 * j] = make_float2(0.f, 0.f);
        __syncthreads();
        wk[sl0] = make_float2(100.f * x[(size_t)r * 2048 + mi0], 0.f);
        wk[sl1] = make_float2(100.f * x[(size_t)r * 2048 + mi1], 0.f);
        __syncthreads();
        {   // plain T0: dft4<-1> on each quad
            {
                const int pb_ = 8 * t;
                const int a_ = SWZ(pb_);
                float4 lo_ = *(const float4*)(&wk[a_]);
                float4 hi_ = *(const float4*)(&wk[a_ + 2]);
                cf u0 = make_float2(lo_.x, lo_.y), u1 = make_float2(lo_.z, lo_.w);
                cf u2 = make_float2(hi_.x, hi_.y), u3 = make_float2(hi_.z, hi_.w);
                dft4r<-1>(u0, u1, u2, u3);
                *(float4*)(&wk[a_])     = make_float4(u0.x, u0.y, u1.x, u1.y);
                *(float4*)(&wk[a_ + 2]) = make_float4(u2.x, u2.y, u3.x, u3.y);
            }
            {
                const int pb_ = 8 * t + 4;
                const int a_ = SWZ(pb_);
                float4 lo_ = *(const float4*)(&wk[a_]);
                float4 hi_ = *(const float4*)(&wk[a_ + 2]);
                cf u0 = make_float2(lo_.x, lo_.y), u1 = make_float2(lo_.z, lo_.w);
                cf u2 = make_float2(hi_.x, hi_.y), u3 = make_float2(hi_.z, hi_.w);
                dft4r<-1>(u0, u1, u2, u3);
                *(float4*)(&wk[a_])     = make_float4(u0.x, u0.y, u1.x, u1.y);
                *(float4*)(&wk[a_ + 2]) = make_float4(u2.x, u2.y, u3.x, u3.y);
            }
        }
        __syncthreads();
        DITMID(A2j, L); __syncthreads();   // T1
        DITMID(A1j, O); __syncthreads();   // T2
        TAILT3(true);   __syncthreads();   // g = u0

        // ---- 99 iterations ----
#pragma unroll 1
        for (int it = 0; it < 99; ++it) {
            HEADS0(false);  __syncthreads();   // S0 (reads g)
            DIFMID(A1j, O); __syncthreads();   // S1
            DIFMID(A2j, L); __syncthreads();   // S2
            QUADMASK(0) QUADMASK(1)            // S3 + mask + T0 in regs
            __syncthreads();
            DITMID(A2j, L); __syncthreads();   // T1
            DITMID(A1j, O); __syncthreads();   // T2
            TAILT3(false);  __syncthreads();   // g update
        }

        // ---- final: out = 0.01 * IDCT(F') ----
        HEADS0(true);   __syncthreads();
        DIFMID(A1j, O); __syncthreads();
        DIFMID(A2j, L); __syncthreads();
#pragma unroll
        for (int q = 0; q < 2; ++q) {          // S3 + reorder to x-order via g
            const int pb_ = 8 * t + 4 * q;
            const int a_ = SWZ(pb_);
            float4 lo_ = *(const float4*)(&wk[a_]);
            float4 hi_ = *(const float4*)(&wk[a_ + 2]);
            cf u0 = make_float2(lo_.x, lo_.y), u1 = make_float2(lo_.z, lo_.w);
            cf u2 = make_float2(hi_.x, hi_.y), u3 = make_float2(hi_.z, hi_.w);
            dft4r<1>(u0, u1, u2, u3);
            {
                const int m = permf(pb_ + 0);
                g[(m < 1024) ? (m << 1) : (4095 - (m << 1))] = 0.01f * u0.x;
            }
            {
                const int m = permf(pb_ + 1);
                g[(m < 1024) ? (m << 1) : (4095 - (m << 1))] = 0.01f * u1.x;
            }
            {
                const int m = permf(pb_ + 2);
                g[(m < 1024) ? (m << 1) : (4095 - (m << 1))] = 0.01f * u2.x;
            }
            {
                const int m = permf(pb_ + 3);
                g[(m < 1024) ? (m << 1) : (4095 - (m << 1))] = 0.01f * u3.x;
            }
        }
        __syncthreads();
#pragma unroll
        for (int j = 0; j < 8; ++j)
            out[(size_t)r * 2048 + t + 256 * j] = g[t + 256 * j];
    }
}

extern "C" void kernel_launch(void* const* d_in, const int* in_sizes, int n_in,
                              void* d_out, int out_size, void* d_ws, size_t ws_size,
                              hipStream_t stream) {
    (void)in_sizes; (void)n_in; (void)out_size; (void)d_ws; (void)ws_size;
    const float* x = (const float*)d_in[0];
    const int* idxs = (const int*)d_in[1];
    ista_fft_kernel<<<dim3(3072 / SPW), dim3(256), 0, stream>>>(x, idxs, (float*)d_out);
}